// Round 8
// baseline (7622.114 us; speedup 1.0000x reference)
//
#include <hip/hip_runtime.h>

// Problem constants (match reference)
#define NB 512   // batch
#define NT 512   // time
#define NI 128   // input dim  (4 k-tiles of 32)
#define NH 256   // hidden dim (8 k-tiles of 32)
#define NG 1024  // 4*NH gate rows
#define NMT 8    // m-tiles of 16 per wave (8 waves * 8 * 16 = 1024 rows)
#define NWAVE 8
#define SPB 16   // sequences per block = MFMA N
#define UPT 8    // hidden units per thread in pointwise (16*256/512)
#define EPSV 1e-5f

// W_hh frag f=(w*8+m)*8+kt  at Wf8[f*64+l]          (512 frags, 512 KB)
// W_ih frag g=(w*8+m)*4+kx  at Wf8[32768 + g*64+l]  (256 frags, 256 KB)
#define WXOFF 32768

typedef short short8 __attribute__((ext_vector_type(8)));  // 8 bf16 = MFMA A/B frag
typedef float f32x4 __attribute__((ext_vector_type(4)));   // MFMA C/D frag

__device__ __forceinline__ unsigned short f32_to_bf16(float f) {
  unsigned int u = __float_as_uint(f);
  u += 0x7fffu + ((u >> 16) & 1u);   // round-to-nearest-even
  return (unsigned short)(u >> 16);
}

// ---------------------------------------------------------------------------
// Prep 1: W_hh and W_ih in MFMA A-fragment order, bf16 (layout unchanged).
// Fragment: lane l holds 8 contiguous-k bf16 of row = w*128+m*16+(l&15),
// k = kt*32 + (l>>4)*8 + e.  Same (lane-group,e)->k convention used for the
// B operand, so the MFMA result is invariant to HW internal k ordering.
// ---------------------------------------------------------------------------
__global__ void prep_kernel(const float* __restrict__ W_ih, const float* __restrict__ W_hh,
                            const float* __restrict__ b_ih, const float* __restrict__ b_hh,
                            unsigned short* __restrict__ Wf, float* __restrict__ bsum) {
  int o = blockIdx.x * blockDim.x + threadIdx.x;   // over (512+256)*512 elements
  int e = o & 7;
  int l = (o >> 3) & 63;
  int f = o >> 9;
  if (f < 512) {              // W_hh frags
    int kt = f & 7, m = (f >> 3) & 7, w = f >> 6;
    int row = w * 128 + m * 16 + (l & 15);
    int k = kt * 32 + ((l >> 4) << 3) + e;
    Wf[o] = f32_to_bf16(W_hh[row * NH + k]);
  } else if (f < 768) {       // W_ih frags
    int g = f - 512;
    int kx = g & 3, m = (g >> 2) & 7, w = g >> 5;
    int row = w * 128 + m * 16 + (l & 15);
    int k = kx * 32 + ((l >> 4) << 3) + e;
    Wf[o] = f32_to_bf16(W_ih[row * NI + k]);
  }
  if (o < NG) bsum[o] = b_ih[o] + b_hh[o];
}

// ---------------------------------------------------------------------------
// Prep 2: rank-sort sequences by length (descending) -> perm (unchanged).
// ---------------------------------------------------------------------------
__global__ void sort_kernel(const int* __restrict__ lengths, int* __restrict__ perm) {
  int i = threadIdx.x;
  __shared__ int L[NB];
  int li = lengths[i];
  L[i] = li;
  __syncthreads();
  int r = 0;
  for (int k = 0; k < NB; ++k) {
    int lk = L[k];
    r += (lk > li) || (lk == li && k < i);
  }
  perm[r] = i;
}

// ---------------------------------------------------------------------------
// Main: one block (512 thr = 8 waves) per 16 sorted sequences (32 blocks).
// All 16 MFMA B-columns are real sequences: col n = seq n (8x less redundant
// MFMA + 8x less weight streaming per sequence than the 2-seq version).
// Per step, fused K=384: gates = W_ih@x_t + W_hh@h + b, 12 k-tiles:
//   kx0-3 streamed, hh0-1 VGPR-resident, hh2 LDS-resident, hh3-7 streamed
//   (rolling <=2 in-flight 32-reg groups; weights L2-hot: 4 blocks/XCD).
// Gates exchanged fp32 via ghp (row stride 18 f32x4 to spread banks).
// Pointwise: thread (s=tid&15, j0=(tid>>4)*8) owns 8 units of seq s; c,h in
// fp32 regs; packed-sequence freeze preserved.  x_t staged bf16 in LDS,
// double-buffered, prefetched 2 steps ahead.
// ---------------------------------------------------------------------------
__global__ __launch_bounds__(512, 1)
void lstm_ln_kernel(const float* __restrict__ X, const int* __restrict__ lengths,
                    const int* __restrict__ perm,
                    const short8* __restrict__ Wf8, const float* __restrict__ bsum,
                    const float* __restrict__ gamma, const float* __restrict__ beta,
                    float* __restrict__ out) {
  const int p = blockIdx.x;
  const int tid = threadIdx.x;
  const int w = tid >> 6;      // wave 0..7
  const int l = tid & 63;      // lane

  __shared__ short8 ldsW[NWAVE * NMT * 64];                  // 64 KB: W_hh kt2
  __shared__ __align__(16) f32x4 ghp[256 * 18];              // 72 KB gates fp32 (pad 16->18)
  __shared__ __align__(16) unsigned short hbuf[SPB][NH + 8]; // 8.3 KB h bf16
  __shared__ __align__(16) unsigned short xs[2][SPB][NI + 8];// 8.5 KB x bf16 dbuf
  __shared__ float redS[NWAVE][SPB];
  __shared__ float redQ[NWAVE][SPB];
  __shared__ float red2[2 * SPB];

  // ---- resident weights ----
  short8 wreg[NMT][2];
#pragma unroll
  for (int m = 0; m < NMT; ++m)
#pragma unroll
    for (int kt = 0; kt < 2; ++kt)
      wreg[m][kt] = Wf8[((w * 8 + m) * 8 + kt) * 64 + l];
#pragma unroll
  for (int m = 0; m < NMT; ++m)
    ldsW[(w * 8 + m) * 64 + l] = Wf8[((w * 8 + m) * 8 + 2) * 64 + l];

  // ---- pointwise mapping: thread -> (seq s, units j0..j0+7) ----
  const int s  = tid & 15;
  const int jq = tid >> 4;       // 0..31
  const int j0 = jq * UPT;
  const int myb = perm[p * SPB + s];
  const int mylen = lengths[myb];
  const int lmax = lengths[perm[p * SPB]];   // perm sorted desc -> first is longest
  float c[UPT], h[UPT];
#pragma unroll
  for (int u = 0; u < UPT; ++u) { c[u] = 0.f; h[u] = 0.f; }

  // ---- x stager mapping: 32 threads per sequence ----
  const int sx = tid >> 5;               // 0..15
  const int xo = (tid & 31) * 4;         // 0..124
  const float* __restrict__ xrow = X + (size_t)perm[p * SPB + sx] * NT * NI + xo;

  // zero hbuf (incl. pad)
  for (int i = tid; i < SPB * (NH + 8); i += 512) (&hbuf[0][0])[i] = 0;

  // stage x for t=0, prefetch t=1
  {
    float4 xv = *(const float4*)(xrow);
    ushort4 px;
    px.x = f32_to_bf16(xv.x); px.y = f32_to_bf16(xv.y);
    px.z = f32_to_bf16(xv.z); px.w = f32_to_bf16(xv.w);
    *(ushort4*)&xs[0][sx][xo] = px;
  }
  float4 xnext = *(const float4*)(xrow + NI);
  __syncthreads();

  const int bn = l & 15;       // B column = sequence
  const int kg = l >> 4;       // k-group within k-tile

  for (int t = 0; t < lmax; ++t) {
    const int cur = t & 1;
    f32x4 acc[NMT];
#pragma unroll
    for (int m = 0; m < NMT; ++m) acc[m] = (f32x4){0.f, 0.f, 0.f, 0.f};

    // rolling stream: issue <=2 groups ahead of consumption
    short8 sA[NMT], sB[NMT];
#pragma unroll
    for (int m = 0; m < NMT; ++m) sA[m] = Wf8[WXOFF + ((w * 8 + m) * 4 + 0) * 64 + l];
#pragma unroll
    for (int m = 0; m < NMT; ++m) sB[m] = Wf8[WXOFF + ((w * 8 + m) * 4 + 1) * 64 + l];
    {
      short8 b = *(const short8*)&hbuf[bn][0 * 32 + kg * 8];
#pragma unroll
      for (int m = 0; m < NMT; ++m)
        acc[m] = __builtin_amdgcn_mfma_f32_16x16x32_bf16(wreg[m][0], b, acc[m], 0, 0, 0);
    }
    {
      short8 b = *(const short8*)&xs[cur][bn][0 * 32 + kg * 8];
#pragma unroll
      for (int m = 0; m < NMT; ++m)
        acc[m] = __builtin_amdgcn_mfma_f32_16x16x32_bf16(sA[m], b, acc[m], 0, 0, 0);
    }
    short8 sC[NMT];
#pragma unroll
    for (int m = 0; m < NMT; ++m) sC[m] = Wf8[WXOFF + ((w * 8 + m) * 4 + 2) * 64 + l];
    {
      short8 b = *(const short8*)&hbuf[bn][1 * 32 + kg * 8];
#pragma unroll
      for (int m = 0; m < NMT; ++m)
        acc[m] = __builtin_amdgcn_mfma_f32_16x16x32_bf16(wreg[m][1], b, acc[m], 0, 0, 0);
    }
    {
      short8 b = *(const short8*)&xs[cur][bn][1 * 32 + kg * 8];
#pragma unroll
      for (int m = 0; m < NMT; ++m)
        acc[m] = __builtin_amdgcn_mfma_f32_16x16x32_bf16(sB[m], b, acc[m], 0, 0, 0);
    }
    short8 sD[NMT];
#pragma unroll
    for (int m = 0; m < NMT; ++m) sD[m] = Wf8[WXOFF + ((w * 8 + m) * 4 + 3) * 64 + l];
    {
      short8 b = *(const short8*)&hbuf[bn][2 * 32 + kg * 8];
#pragma unroll
      for (int m = 0; m < NMT; ++m)
        acc[m] = __builtin_amdgcn_mfma_f32_16x16x32_bf16(ldsW[(w * 8 + m) * 64 + l], b,
                                                         acc[m], 0, 0, 0);
    }
    {
      short8 b = *(const short8*)&xs[cur][bn][2 * 32 + kg * 8];
#pragma unroll
      for (int m = 0; m < NMT; ++m)
        acc[m] = __builtin_amdgcn_mfma_f32_16x16x32_bf16(sC[m], b, acc[m], 0, 0, 0);
    }
    short8 sE[NMT];
#pragma unroll
    for (int m = 0; m < NMT; ++m) sE[m] = Wf8[((w * 8 + m) * 8 + 3) * 64 + l];
    {
      short8 b = *(const short8*)&xs[cur][bn][3 * 32 + kg * 8];
#pragma unroll
      for (int m = 0; m < NMT; ++m)
        acc[m] = __builtin_amdgcn_mfma_f32_16x16x32_bf16(sD[m], b, acc[m], 0, 0, 0);
    }
    short8 sF[NMT];
#pragma unroll
    for (int m = 0; m < NMT; ++m) sF[m] = Wf8[((w * 8 + m) * 8 + 4) * 64 + l];
    {
      short8 b = *(const short8*)&hbuf[bn][3 * 32 + kg * 8];
#pragma unroll
      for (int m = 0; m < NMT; ++m)
        acc[m] = __builtin_amdgcn_mfma_f32_16x16x32_bf16(sE[m], b, acc[m], 0, 0, 0);
    }
    short8 sG[NMT];
#pragma unroll
    for (int m = 0; m < NMT; ++m) sG[m] = Wf8[((w * 8 + m) * 8 + 5) * 64 + l];
    {
      short8 b = *(const short8*)&hbuf[bn][4 * 32 + kg * 8];
#pragma unroll
      for (int m = 0; m < NMT; ++m)
        acc[m] = __builtin_amdgcn_mfma_f32_16x16x32_bf16(sF[m], b, acc[m], 0, 0, 0);
    }
    short8 sH[NMT];
#pragma unroll
    for (int m = 0; m < NMT; ++m) sH[m] = Wf8[((w * 8 + m) * 8 + 6) * 64 + l];
    {
      short8 b = *(const short8*)&hbuf[bn][5 * 32 + kg * 8];
#pragma unroll
      for (int m = 0; m < NMT; ++m)
        acc[m] = __builtin_amdgcn_mfma_f32_16x16x32_bf16(sG[m], b, acc[m], 0, 0, 0);
    }
    short8 sI[NMT];
#pragma unroll
    for (int m = 0; m < NMT; ++m) sI[m] = Wf8[((w * 8 + m) * 8 + 7) * 64 + l];
    {
      short8 b = *(const short8*)&hbuf[bn][6 * 32 + kg * 8];
#pragma unroll
      for (int m = 0; m < NMT; ++m)
        acc[m] = __builtin_amdgcn_mfma_f32_16x16x32_bf16(sH[m], b, acc[m], 0, 0, 0);
    }
    {
      short8 b = *(const short8*)&hbuf[bn][7 * 32 + kg * 8];
#pragma unroll
      for (int m = 0; m < NMT; ++m)
        acc[m] = __builtin_amdgcn_mfma_f32_16x16x32_bf16(sI[m], b, acc[m], 0, 0, 0);
    }

    // write gates (+bias, fp32).  D: lane l, reg r -> row (l>>4)*4+r, col l&15.
#pragma unroll
    for (int m = 0; m < NMT; ++m) {
      int rg = w * 128 + m * 16 + kg * 4;
      f32x4 bv = *(const f32x4*)&bsum[rg];
      ghp[(w * 32 + m * 4 + kg) * 18 + bn] = acc[m] + bv;
    }
    __syncthreads();

    // ---------------- pointwise: 8 units of seq s ----------------
    {
      const bool live = (t < mylen);
      float pi[UPT], pf[UPT], pg[UPT], po[UPT];
#pragma unroll
      for (int d = 0; d < 2; ++d) {
        f32x4 qi = ghp[(0 * 64 + jq * 2 + d) * 18 + s];
        f32x4 qf = ghp[(1 * 64 + jq * 2 + d) * 18 + s];
        f32x4 qg = ghp[(2 * 64 + jq * 2 + d) * 18 + s];
        f32x4 qo = ghp[(3 * 64 + jq * 2 + d) * 18 + s];
#pragma unroll
        for (int e = 0; e < 4; ++e) {
          pi[d * 4 + e] = qi[e]; pf[d * 4 + e] = qf[e];
          pg[d * 4 + e] = qg[e]; po[d * 4 + e] = qo[e];
        }
      }
      if (live) {
        short8 hb;
#pragma unroll
        for (int u = 0; u < UPT; ++u) {
          float ig = 1.f / (1.f + __expf(-pi[u]));
          float fg = 1.f / (1.f + __expf(-pf[u]));
          float gv = 1.f - 2.f / (1.f + __expf(2.f * pg[u]));
          float og = 1.f / (1.f + __expf(-po[u]));
          c[u] = fg * c[u] + ig * gv;
          h[u] = og * (1.f - 2.f / (1.f + __expf(2.f * c[u])));
          hb[u] = (short)f32_to_bf16(h[u]);
        }
        *(short8*)&hbuf[s][j0] = hb;
      }
      // stage x for t+1; prefetch t+2
      ushort4 px;
      px.x = f32_to_bf16(xnext.x); px.y = f32_to_bf16(xnext.y);
      px.z = f32_to_bf16(xnext.z); px.w = f32_to_bf16(xnext.w);
      *(ushort4*)&xs[(t + 1) & 1][sx][xo] = px;
      int tn = (t + 2 < NT) ? (t + 2) : (NT - 1);
      xnext = *(const float4*)(xrow + (size_t)tn * NI);
    }
    __syncthreads();
  }

  // ---- LayerNorm per sequence (reduce over 32 threads sharing s) ----
  float S = 0.f, Q = 0.f;
#pragma unroll
  for (int u = 0; u < UPT; ++u) { S += h[u]; Q += h[u] * h[u]; }
  S += __shfl_xor(S, 16); Q += __shfl_xor(Q, 16);
  S += __shfl_xor(S, 32); Q += __shfl_xor(Q, 32);
  if (l < SPB) { redS[w][l] = S; redQ[w][l] = Q; }
  __syncthreads();
  if (tid < SPB) {
    float Sa = 0.f, Qa = 0.f;
#pragma unroll
    for (int ww = 0; ww < NWAVE; ++ww) { Sa += redS[ww][tid]; Qa += redQ[ww][tid]; }
    float mu = Sa * (1.f / NH);
    red2[tid] = mu;
    red2[SPB + tid] = rsqrtf(Qa * (1.f / NH) - mu * mu + EPSV);
  }
  __syncthreads();
  {
    float mu = red2[s], rstd = red2[SPB + s];
#pragma unroll
    for (int u = 0; u < UPT; ++u) {
      int j = j0 + u;
      out[(size_t)myb * NH + j] = (h[u] - mu) * rstd * gamma[j] + beta[j];
    }
  }
}

extern "C" void kernel_launch(void* const* d_in, const int* in_sizes, int n_in,
                              void* d_out, int out_size, void* d_ws, size_t ws_size,
                              hipStream_t stream) {
  const float* X       = (const float*)d_in[0];
  const int*   lengths = (const int*)d_in[1];
  const float* W_ih    = (const float*)d_in[2];
  const float* W_hh    = (const float*)d_in[3];
  const float* b_ih    = (const float*)d_in[4];
  const float* b_hh    = (const float*)d_in[5];
  const float* gamma   = (const float*)d_in[6];
  const float* beta    = (const float*)d_in[7];
  float* out = (float*)d_out;

  // workspace layout (768 KB weights + 4 KB bsum + 2 KB perm)
  unsigned short* Wf = (unsigned short*)d_ws;
  float* bsum = (float*)((char*)d_ws + (size_t)768 * 512 * sizeof(unsigned short));
  int* perm = (int*)((char*)bsum + NG * sizeof(float));

  int total = 768 * 512;   // (512 W_hh + 256 W_ih frags) * 512 elems
  prep_kernel<<<(total + 255) / 256, 256, 0, stream>>>(W_ih, W_hh, b_ih, b_hh, Wf, bsum);
  sort_kernel<<<1, NB, 0, stream>>>(lengths, perm);
  lstm_ln_kernel<<<NB / SPB, 512, 0, stream>>>(X, lengths, perm, (const short8*)Wf, bsum,
                                               gamma, beta, out);
}